// Round 10
// baseline (86392.236 us; speedup 1.0000x reference)
//
#include <hip/hip_runtime.h>

// LSTMRecursiveModel: B=16, L=96, H=256, NL=2, O=32. 3168 sequential steps.
// Single-XCD persistent kernel: 32 WGs x 512 thr, 1 WG/CU (LDS-forced), on the
// first XCD to collect 32 WGs (R5/R7-proven claim). Phase p = L0(p) || L1(p-1).
//
// Round 10: R9 byte-identical EXCEPT the barrier. R7/R9 both burned ~20us/phase
// in the 1024-lane atomic poll (MALL atomic queue congestion: the release store
// waits behind thousands of in-flight polls). New two-level low-pressure
// barrier: 32 arrival stores -> master WG (32 lanes, s_sleep backoff) polls
// flags -> 1 gen store -> 31 single-lane pollers on gen (s_sleep backoff).
// <=63 spinning lanes instead of 1024. Then R9-proven acquire fence (L1 inv)
// + __syncthreads. Data path unchanged: plain stores/loads via home-XCD L2.

#define NWORK 32
#define NLAUNCH 256
#define LASTP 3169
#define BSTRIDE 290
#define CSTRIDE 18
#define H1OFF 4640      // 16*290
#define XOFF 9280       // x stage base; lds total 9296 floats

typedef float fx4 __attribute__((ext_vector_type(4)));

__device__ __forceinline__ float sigm(float x) { return 1.0f / (1.0f + expf(-x)); }

// ws float layout: h0buf[2][16][256]@0, h1buf@8192, predbuf[32][16]@16384,
// flags(32 u32, 64B-strided)@17024, gen@17568, arr[8]@17600, home@17608
__global__ void init_kernel(float* __restrict__ out, float* __restrict__ ws) {
  int i = blockIdx.x * blockDim.x + threadIdx.x;
  if (i < 16 * 96) out[i] = 0.0f;
  for (int j = i; j < 17608; j += gridDim.x * blockDim.x) ws[j] = 0.0f;
  if (i == 0) ((unsigned*)ws)[17608] = 0xFFFFFFFFu;
}

extern "C" __global__ __launch_bounds__(512, 2) void lstm_x10(
    const float* __restrict__ x_enc,
    const float* __restrict__ Wih0, const float* __restrict__ Whh0,
    const float* __restrict__ bih0, const float* __restrict__ bhh0,
    const float* __restrict__ Wih1, const float* __restrict__ Whh1,
    const float* __restrict__ bih1, const float* __restrict__ bhh1,
    const float* __restrict__ fc_w, const float* __restrict__ fc_b,
    float* __restrict__ out, float* __restrict__ ws) {
  const int tid = threadIdx.x;
  __shared__ int s_rank;
  extern __shared__ float lds[];

  unsigned* flags = (unsigned*)(ws + 17024);
  unsigned* gen = (unsigned*)(ws + 17568);
  unsigned* arr = (unsigned*)(ws + 17600);
  unsigned* home = (unsigned*)(ws + 17608);
  float* predbuf = ws + 16384;

  // ---- claim: first XCD to collect 32 WGs wins (R5/R7-proven) ----
  if (tid == 0) {
    unsigned xcc;
    asm volatile("s_getreg_b32 %0, hwreg(HW_REG_XCC_ID)" : "=s"(xcc));
    xcc &= 7u;
    unsigned idx = __hip_atomic_fetch_add(&arr[xcc], 1u, __ATOMIC_ACQ_REL,
                                          __HIP_MEMORY_SCOPE_AGENT);
    int rank = -1;
    if (idx < NWORK) {
      if (idx == NWORK - 1) {
        unsigned expv = 0xFFFFFFFFu;
        __hip_atomic_compare_exchange_strong(home, &expv, xcc, __ATOMIC_ACQ_REL,
                                             __ATOMIC_RELAXED, __HIP_MEMORY_SCOPE_AGENT);
      }
      unsigned hv;
      while ((hv = __hip_atomic_load(home, __ATOMIC_RELAXED,
                                     __HIP_MEMORY_SCOPE_AGENT)) == 0xFFFFFFFFu) {}
      if (hv == xcc) rank = (int)idx;
    }
    s_rank = rank;
  }
  __syncthreads();
  const int rank = s_rank;
  if (rank < 0) return;

  const int wv = tid >> 6, lane = tid & 63;
  const int g = lane & 1, kl = lane >> 1;    // batch-group (8 b), k-slice (32)
  const int bown = g * 8 + (kl & 7);
  const int cc = rank * 8 + wv;              // owned column, both layers

  // ---- stationary weights -> VGPRs, pinned (96 floats/lane) ----
  fx4 W0[2][4], W1[4][4];
  float bias0[4], xw0[4], bias1[4];
#pragma unroll
  for (int q = 0; q < 4; ++q) {
    int row = q * 256 + cc;
    W0[0][q] = *(const fx4*)(Whh0 + row * 256 + kl * 4);
    W0[1][q] = *(const fx4*)(Whh0 + row * 256 + 128 + kl * 4);
    W1[0][q] = *(const fx4*)(Wih1 + row * 256 + kl * 4);
    W1[1][q] = *(const fx4*)(Wih1 + row * 256 + 128 + kl * 4);
    W1[2][q] = *(const fx4*)(Whh1 + row * 256 + kl * 4);
    W1[3][q] = *(const fx4*)(Whh1 + row * 256 + 128 + kl * 4);
    bias0[q] = bih0[row] + bhh0[row];
    xw0[q] = Wih0[row];                      // Wih0 is (1024,1)
    bias1[q] = bih1[row] + bhh1[row];
  }
#pragma unroll
  for (int q = 0; q < 4; ++q) {
    asm volatile("" : "+v"(W0[0][q]), "+v"(W0[1][q]));
    asm volatile("" : "+v"(W1[0][q]), "+v"(W1[1][q]), "+v"(W1[2][q]), "+v"(W1[3][q]));
  }

  const int k0 = kl & 1, k1 = (kl >> 1) & 1, k2 = (kl >> 2) & 1;

  // fold-reduce: a[4][8] (gate,bb) over 32 kl-lanes -> aq[4] for bb=kl&7.
  auto fold = [&](float (&a)[4][8], float (&aq)[4]) {
    float b2[4][4];
#pragma unroll
    for (int q = 0; q < 4; ++q)
#pragma unroll
      for (int u = 0; u < 4; ++u) {
        float snd = k0 ? a[q][2 * u] : a[q][2 * u + 1];
        float rcv = __shfl_xor(snd, 2);
        b2[q][u] = (k0 ? a[q][2 * u + 1] : a[q][2 * u]) + rcv;
      }
    float c2[4][2];
#pragma unroll
    for (int q = 0; q < 4; ++q)
#pragma unroll
      for (int u = 0; u < 2; ++u) {
        float snd = k1 ? b2[q][2 * u] : b2[q][2 * u + 1];
        float rcv = __shfl_xor(snd, 4);
        c2[q][u] = (k1 ? b2[q][2 * u + 1] : b2[q][2 * u]) + rcv;
      }
#pragma unroll
    for (int q = 0; q < 4; ++q) {
      float snd = k2 ? c2[q][0] : c2[q][1];
      float rcv = __shfl_xor(snd, 8);
      aq[q] = (k2 ? c2[q][1] : c2[q][0]) + rcv;
      aq[q] += __shfl_xor(aq[q], 16);
      aq[q] += __shfl_xor(aq[q], 32);
    }
  };

  double cs0 = 0.0, cs1 = 0.0;

  for (int p = 0; p <= LASTP; ++p) {
    const float* h0prev = ws + ((p + 1) & 1) * 4096;
    float* h0cur = ws + (p & 1) * 4096;
    const float* h1prev = ws + 8192 + (p & 1) * 4096;
    float* h1cur = ws + 8192 + ((p + 1) & 1) * 4096;

    // ---- stage h0prev + h1prev -> LDS: 8 plain b64 loads (L1 invalidated
    // by last phase's acquire fence; lines served by home-XCD L2) ----
    unsigned long long sv[8];
#pragma unroll
    for (int m = 0; m < 8; ++m) {
      int i = tid + m * 512;   // 0..4095
      const float* src = (i < 2048) ? (h0prev + 2 * i) : (h1prev + 2 * (i - 2048));
      sv[m] = *(const unsigned long long*)src;
    }
    float xs = 0.0f;
    const bool dox = (tid < 16) && (p <= 3167);
    if (dox) {
      int s = p;
      if (s < 96) {
        xs = x_enc[tid * 96 + s];
      } else {
        int sk = s - 96;
        int k = sk / 96;
        int t = sk - k * 96;
        xs = (t < 96 - k) ? x_enc[tid * 96 + k + t]
                          : predbuf[(t - 96 + k) * 16 + tid];
      }
    }
#pragma unroll
    for (int m = 0; m < 8; ++m) {
      int i = tid + m * 512;
      int ii = (i < 2048) ? i : (i - 2048);
      int b = ii >> 7, r = ii & 127;
      int idx = ((i < 2048) ? 0 : H1OFF) + b * BSTRIDE + (r >> 3) * CSTRIDE + 2 * (r & 7);
      union { unsigned long long u; float2 f; } c; c.u = sv[m];
      *(float2*)&lds[idx] = c.f;
    }
    if (dox) lds[XOFF + tid] = xs;
    __syncthreads();

    const int cbase = (kl >> 2) * CSTRIDE + 4 * (kl & 3);

    // ---- layer 0, step p ----
    if (p <= 3167) {
      float a[4][8];
#pragma unroll
      for (int q = 0; q < 4; ++q)
#pragma unroll
        for (int bb = 0; bb < 8; ++bb) a[q][bb] = 0.0f;
#pragma unroll
      for (int bb = 0; bb < 8; ++bb) {
        const float* hb = lds + (g * 8 + bb) * BSTRIDE;
        float2 x0 = *(const float2*)(hb + cbase);
        float2 x1 = *(const float2*)(hb + cbase + 2);
        float2 x2 = *(const float2*)(hb + 8 * CSTRIDE + cbase);
        float2 x3 = *(const float2*)(hb + 8 * CSTRIDE + cbase + 2);
#pragma unroll
        for (int q = 0; q < 4; ++q) {
          a[q][bb] += W0[0][q][0] * x0.x + W0[0][q][1] * x0.y +
                      W0[0][q][2] * x1.x + W0[0][q][3] * x1.y +
                      W0[1][q][0] * x2.x + W0[1][q][1] * x2.y +
                      W0[1][q][2] * x3.x + W0[1][q][3] * x3.y;
        }
      }
      float aq[4];
      fold(a, aq);
      float xv = lds[XOFF + bown];
      float gI = aq[0] + xv * xw0[0] + bias0[0];
      float gF = aq[1] + xv * xw0[1] + bias0[1];
      float gG = aq[2] + xv * xw0[2] + bias0[2];
      float gO = aq[3] + xv * xw0[3] + bias0[3];
      double cn = (double)sigm(gF) * cs0 + (double)(sigm(gI) * tanhf(gG));
      float hn = sigm(gO) * tanhf((float)cn);
      cs0 = cn;
      if (kl < 8) h0cur[bown * 256 + cc] = hn;
    }

    // ---- layer 1, step p-1 ----
    if (p >= 1 && p <= 3168) {
      float a[4][8];
#pragma unroll
      for (int q = 0; q < 4; ++q)
#pragma unroll
        for (int bb = 0; bb < 8; ++bb) a[q][bb] = 0.0f;
#pragma unroll
      for (int bb = 0; bb < 8; ++bb) {
        const float* hb0 = lds + (g * 8 + bb) * BSTRIDE;
        const float* hb1 = hb0 + H1OFF;
        float2 x0 = *(const float2*)(hb0 + cbase);
        float2 x1 = *(const float2*)(hb0 + cbase + 2);
        float2 x2 = *(const float2*)(hb0 + 8 * CSTRIDE + cbase);
        float2 x3 = *(const float2*)(hb0 + 8 * CSTRIDE + cbase + 2);
        float2 y0 = *(const float2*)(hb1 + cbase);
        float2 y1 = *(const float2*)(hb1 + cbase + 2);
        float2 y2 = *(const float2*)(hb1 + 8 * CSTRIDE + cbase);
        float2 y3 = *(const float2*)(hb1 + 8 * CSTRIDE + cbase + 2);
#pragma unroll
        for (int q = 0; q < 4; ++q) {
          a[q][bb] += W1[0][q][0] * x0.x + W1[0][q][1] * x0.y +
                      W1[0][q][2] * x1.x + W1[0][q][3] * x1.y +
                      W1[1][q][0] * x2.x + W1[1][q][1] * x2.y +
                      W1[1][q][2] * x3.x + W1[1][q][3] * x3.y +
                      W1[2][q][0] * y0.x + W1[2][q][1] * y0.y +
                      W1[2][q][2] * y1.x + W1[2][q][3] * y1.y +
                      W1[3][q][0] * y2.x + W1[3][q][1] * y2.y +
                      W1[3][q][2] * y3.x + W1[3][q][3] * y3.y;
        }
      }
      float aq[4];
      fold(a, aq);
      float gI = aq[0] + bias1[0];
      float gF = aq[1] + bias1[1];
      float gG = aq[2] + bias1[2];
      float gO = aq[3] + bias1[3];
      double cn = (double)sigm(gF) * cs1 + (double)(sigm(gI) * tanhf(gG));
      float hn = sigm(gO) * tanhf((float)cn);
      cs1 = cn;
      if (kl < 8) h1cur[bown * 256 + cc] = hn;
    }

    // ---- prediction: h1(191+96jp) = staged h1s this phase ----
    if (rank == 0 && wv == 0 && p >= 193 && ((p - 193) % 96) == 0) {
      int jp = (p - 193) / 96;
      if (jp < 32) {
        int pb = lane & 15, q4 = lane >> 4;
        float acc = 0.0f;
#pragma unroll
        for (int j = 0; j < 32; ++j) {
          int kk = q4 * 64 + 2 * j;
          float2 hv = *(const float2*)&lds[H1OFF + pb * BSTRIDE +
                                           (kk >> 4) * CSTRIDE + (kk & 15)];
          acc += hv.x * fc_w[kk] + hv.y * fc_w[kk + 1];
        }
        acc += __shfl_xor(acc, 16);
        acc += __shfl_xor(acc, 32);
        if (q4 == 0) {
          float pv = acc + fc_b[0];
          predbuf[jp * 16 + pb] = pv;
          out[pb * 96 + jp] = pv;
        }
      }
    }

    // ---- two-level low-pressure barrier ----
    __syncthreads();   // compiler drains vmcnt(0): h stores are in L2
    const unsigned tgt = (unsigned)(p + 1);
    if (tid == 0) {
      __hip_atomic_store(&flags[rank * 16], tgt, __ATOMIC_RELAXED,
                         __HIP_MEMORY_SCOPE_AGENT);
    }
    if (wv == 0) {
      if (rank == 0) {
        if (lane < NWORK) {
          while (!__all(__hip_atomic_load(&flags[lane * 16], __ATOMIC_RELAXED,
                                          __HIP_MEMORY_SCOPE_AGENT) >= tgt)) {
            asm volatile("s_sleep 2");
          }
        }
        if (lane == 0) {
          __hip_atomic_store(gen, tgt, __ATOMIC_RELAXED, __HIP_MEMORY_SCOPE_AGENT);
        }
      } else {
        if (lane == 0) {
          while (__hip_atomic_load(gen, __ATOMIC_RELAXED,
                                   __HIP_MEMORY_SCOPE_AGENT) < tgt) {
            asm volatile("s_sleep 2");
          }
        }
      }
      __builtin_amdgcn_fence(__ATOMIC_ACQUIRE, "agent");   // L1 invalidate
    }
    __syncthreads();   // waves 1-7 ordered behind the invalidate
  }
}

extern "C" void kernel_launch(void* const* d_in, const int* in_sizes, int n_in,
                              void* d_out, int out_size, void* d_ws, size_t ws_size,
                              hipStream_t stream) {
  const float* x_enc = (const float*)d_in[0];
  const float* Wih0 = (const float*)d_in[4];
  const float* Whh0 = (const float*)d_in[5];
  const float* bih0 = (const float*)d_in[6];
  const float* bhh0 = (const float*)d_in[7];
  const float* Wih1 = (const float*)d_in[8];
  const float* Whh1 = (const float*)d_in[9];
  const float* bih1 = (const float*)d_in[10];
  const float* bhh1 = (const float*)d_in[11];
  const float* fc_w = (const float*)d_in[12];
  const float* fc_b = (const float*)d_in[13];
  float* out = (float*)d_out;
  float* ws = (float*)d_ws;

  hipLaunchKernelGGL(init_kernel, dim3(8), dim3(256), 0, stream, out, ws);

  const int ldsBytes = 82944;   // ~37KB used; >80KB forces 1 WG/CU residency
  static int attrSet = 0;
  if (!attrSet) {
    (void)hipFuncSetAttribute((const void*)lstm_x10,
                              hipFuncAttributeMaxDynamicSharedMemorySize, ldsBytes);
    attrSet = 1;
  }

  hipLaunchKernelGGL(lstm_x10, dim3(NLAUNCH), dim3(512), ldsBytes, stream,
                     x_enc, Wih0, Whh0, bih0, bhh0, Wih1, Whh1, bih1, bhh1,
                     fc_w, fc_b, out, ws);
}

// Round 11
// 46181.232 us; speedup vs baseline: 1.8707x; 1.8707x over previous
//
#include <hip/hip_runtime.h>

// LSTMRecursiveModel: B=16, L=96, H=256, NL=2, O=32. 3168 sequential steps.
//
// Round 11: BATCH-DECOMPOSED CLUSTERS. The recurrence is independent per
// batch (h0_b,c0_b,h1_b,c1_b, preds, and x-feedback all stay within batch b).
// 8 independent clusters, one per XCD, 2 batches each. Cluster = 8 WGs x 512
// thr on 8 CUs (claim: first 8 WGs per XCD via one fetch_add). No cooperative
// launch, no cross-cluster traffic, no global barrier -- each cluster syncs
// only its 8 WGs, exchanging 4KB of h per phase.
// All cross-WG data/flags via relaxed agent atomics (R4/R7-proven correct;
// no fences -> no sc0/fence hang classes). Weights VGPR-resident:
// 192 floats/lane (WG owns 32 cols of both layers; wave 4 cols; lane =
// (cs=lane>>4 col, kl=lane&15 k-slice of 16)). Per phase p: L0(p) || L1(p-1),
// 384 FMA/lane, 4-step shfl_xor k-reduce, activation+double cell state on
// kl<2 lanes (kl = local batch).
// LDS stage: pad-20 chunks (H0[b][kl][20], H1 at 640, X at 1280) -> aligned
// float4 reads, same-address broadcast across cs groups, ~0 bank conflicts.

#define NWGC 8       // WGs per cluster
#define LASTP 3169

typedef float fx4 __attribute__((ext_vector_type(4)));

__device__ __forceinline__ float sigm(float x) { return 1.0f / (1.0f + expf(-x)); }

__device__ __forceinline__ unsigned long long ald64(const float* p) {
  return __hip_atomic_load((const unsigned long long*)p, __ATOMIC_RELAXED,
                           __HIP_MEMORY_SCOPE_AGENT);
}
__device__ __forceinline__ float ald32(const float* p) {
  unsigned u = __hip_atomic_load((const unsigned*)p, __ATOMIC_RELAXED,
                                 __HIP_MEMORY_SCOPE_AGENT);
  union { unsigned u; float f; } c; c.u = u; return c.f;
}
__device__ __forceinline__ void ast32(float* p, float f) {
  union { unsigned u; float f; } c; c.f = f;
  __hip_atomic_store((unsigned*)p, c.u, __ATOMIC_RELAXED, __HIP_MEMORY_SCOPE_AGENT);
}

// ws float layout:
//   cluster c data @ c*4096 : h0[parity(2)][b(2)][256] (1024), h1 same @ +1024
//   predbuf @ 32768 + c*64  : [jp(32)][lb(2)]
//   flags   @ 33280 + c*128 uints (rank stride 16 uints = 64B)
//   arr[8]  @ 34304 (uints)
__global__ void init_kernel(float* __restrict__ out, float* __restrict__ ws) {
  int i = blockIdx.x * blockDim.x + threadIdx.x;
  if (i < 16 * 96) out[i] = 0.0f;
  for (int j = i; j < 34312; j += gridDim.x * blockDim.x) ws[j] = 0.0f;
}

extern "C" __global__ __launch_bounds__(512, 2) void lstm_bc(
    const float* __restrict__ x_enc,
    const float* __restrict__ Wih0, const float* __restrict__ Whh0,
    const float* __restrict__ bih0, const float* __restrict__ bhh0,
    const float* __restrict__ Wih1, const float* __restrict__ Whh1,
    const float* __restrict__ bih1, const float* __restrict__ bhh1,
    const float* __restrict__ fc_w, const float* __restrict__ fc_b,
    float* __restrict__ out, float* __restrict__ ws) {
  const int tid = threadIdx.x;
  __shared__ int s_rank, s_c;
  extern __shared__ float lds[];   // H0: b*320+kl*20 ; H1 @640 ; X @1280

  unsigned* arr = (unsigned*)(ws + 34304);

  // ---- claim: first 8 WGs on each XCD work for that XCD's cluster ----
  if (tid == 0) {
    unsigned xcc;
    asm volatile("s_getreg_b32 %0, hwreg(HW_REG_XCC_ID)" : "=s"(xcc));
    xcc &= 7u;
    unsigned idx = __hip_atomic_fetch_add(&arr[xcc], 1u, __ATOMIC_ACQ_REL,
                                          __HIP_MEMORY_SCOPE_AGENT);
    s_rank = (idx < NWGC) ? (int)idx : -1;
    s_c = (int)xcc;
  }
  __syncthreads();
  const int rank = s_rank, c = s_c;
  if (rank < 0) return;

  const int wv = tid >> 6, lane = tid & 63;
  const int cs = lane >> 4, kl = lane & 15;   // col-sub (4), k-slice (16x16)
  const int cc = rank * 32 + wv * 4 + cs;     // owned column, both layers

  float* cb = ws + c * 4096;
  float* predb = ws + 32768 + c * 64;
  unsigned* flags = (unsigned*)(ws + 33280) + c * 128;

  // ---- stationary weights -> VGPRs (192 floats/lane), pinned ----
  fx4 W0[4][4], W1[4][8];
  float bias0[4], xw0[4], bias1[4];
#pragma unroll
  for (int g = 0; g < 4; ++g) {
    int row = g * 256 + cc;
#pragma unroll
    for (int j = 0; j < 4; ++j) {
      W0[g][j] = *(const fx4*)(Whh0 + row * 256 + kl * 16 + 4 * j);
      W1[g][j] = *(const fx4*)(Wih1 + row * 256 + kl * 16 + 4 * j);
      W1[g][4 + j] = *(const fx4*)(Whh1 + row * 256 + kl * 16 + 4 * j);
    }
    bias0[g] = bih0[row] + bhh0[row];
    xw0[g] = Wih0[row];                        // Wih0 is (1024,1)
    bias1[g] = bih1[row] + bhh1[row];
  }
#pragma unroll
  for (int g = 0; g < 4; ++g) {
    asm volatile("" : "+v"(W0[g][0]), "+v"(W0[g][1]), "+v"(W0[g][2]), "+v"(W0[g][3]));
    asm volatile("" : "+v"(W1[g][0]), "+v"(W1[g][1]), "+v"(W1[g][2]), "+v"(W1[g][3]));
    asm volatile("" : "+v"(W1[g][4]), "+v"(W1[g][5]), "+v"(W1[g][6]), "+v"(W1[g][7]));
  }

  double cs0 = 0.0, cs1 = 0.0;   // cell states: lane kl<2 owns (cc, b=kl)

  for (int p = 0; p <= LASTP; ++p) {
    const float* h0prev = cb + ((p + 1) & 1) * 512;
    float* h0cur = cb + (p & 1) * 512;
    const float* h1prev = cb + 1024 + (p & 1) * 512;
    float* h1cur = cb + 1024 + ((p + 1) & 1) * 512;

    // ---- stage h0prev + h1prev (1024 floats) -> LDS: 1 atomic b64/thread ----
    {
      int flat, dstbase;
      const float* src;
      if (tid < 256) { flat = 2 * tid; src = h0prev + flat; dstbase = 0; }
      else { flat = 2 * (tid - 256); src = h1prev + flat; dstbase = 640; }
      unsigned long long v = ald64(src);
      int b = flat >> 8, col = flat & 255;
      int idx = dstbase + b * 320 + (col >> 4) * 20 + (col & 15);
      union { unsigned long long u; float2 f; } u2; u2.u = v;
      lds[idx] = u2.f.x;
      lds[idx + 1] = u2.f.y;
      if ((tid >> 1) == 252 && p <= 3167) {   // threads 504,505 stage x
        int lb = tid & 1, gb = 2 * c + lb;
        float xs;
        if (p < 96) {
          xs = x_enc[gb * 96 + p];
        } else {
          int sk = p - 96;
          int k = sk / 96;
          int t2 = sk - k * 96;
          xs = (t2 < 96 - k) ? x_enc[gb * 96 + k + t2]
                             : ald32(predb + (t2 - 96 + k) * 2 + lb);
        }
        lds[1280 + lb] = xs;
      }
    }
    __syncthreads();

    // ---- layer 0, step p ----
    if (p <= 3167) {
      float a0[4][2];
#pragma unroll
      for (int g = 0; g < 4; ++g) { a0[g][0] = 0.0f; a0[g][1] = 0.0f; }
#pragma unroll
      for (int b = 0; b < 2; ++b) {
        fx4 hv[4];
#pragma unroll
        for (int j = 0; j < 4; ++j) hv[j] = *(const fx4*)&lds[b * 320 + kl * 20 + 4 * j];
#pragma unroll
        for (int g = 0; g < 4; ++g)
#pragma unroll
          for (int j = 0; j < 4; ++j)
            a0[g][b] += W0[g][j][0] * hv[j][0] + W0[g][j][1] * hv[j][1] +
                        W0[g][j][2] * hv[j][2] + W0[g][j][3] * hv[j][3];
      }
#pragma unroll
      for (int m = 1; m <= 8; m <<= 1)
#pragma unroll
        for (int g = 0; g < 4; ++g) {
          a0[g][0] += __shfl_xor(a0[g][0], m);
          a0[g][1] += __shfl_xor(a0[g][1], m);
        }
      if (kl < 2) {
        int b = kl;
        float xv = lds[1280 + b];
        float gI = a0[0][b] + xv * xw0[0] + bias0[0];
        float gF = a0[1][b] + xv * xw0[1] + bias0[1];
        float gG = a0[2][b] + xv * xw0[2] + bias0[2];
        float gO = a0[3][b] + xv * xw0[3] + bias0[3];
        double cn = (double)sigm(gF) * cs0 + (double)(sigm(gI) * tanhf(gG));
        float hn = sigm(gO) * tanhf((float)cn);
        cs0 = cn;
        ast32(h0cur + b * 256 + cc, hn);
      }
    }

    // ---- layer 1, step p-1 (inputs: h0'(p-1)=staged H0, h1(p-2)=staged H1) ----
    if (p >= 1 && p <= 3168) {
      float a1[4][2];
#pragma unroll
      for (int g = 0; g < 4; ++g) { a1[g][0] = 0.0f; a1[g][1] = 0.0f; }
#pragma unroll
      for (int b = 0; b < 2; ++b) {
        fx4 hv0[4], hv1[4];
#pragma unroll
        for (int j = 0; j < 4; ++j) {
          hv0[j] = *(const fx4*)&lds[b * 320 + kl * 20 + 4 * j];
          hv1[j] = *(const fx4*)&lds[640 + b * 320 + kl * 20 + 4 * j];
        }
#pragma unroll
        for (int g = 0; g < 4; ++g)
#pragma unroll
          for (int j = 0; j < 4; ++j)
            a1[g][b] += W1[g][j][0] * hv0[j][0] + W1[g][j][1] * hv0[j][1] +
                        W1[g][j][2] * hv0[j][2] + W1[g][j][3] * hv0[j][3] +
                        W1[g][4 + j][0] * hv1[j][0] + W1[g][4 + j][1] * hv1[j][1] +
                        W1[g][4 + j][2] * hv1[j][2] + W1[g][4 + j][3] * hv1[j][3];
      }
#pragma unroll
      for (int m = 1; m <= 8; m <<= 1)
#pragma unroll
        for (int g = 0; g < 4; ++g) {
          a1[g][0] += __shfl_xor(a1[g][0], m);
          a1[g][1] += __shfl_xor(a1[g][1], m);
        }
      if (kl < 2) {
        int b = kl;
        float gI = a1[0][b] + bias1[0];
        float gF = a1[1][b] + bias1[1];
        float gG = a1[2][b] + bias1[2];
        float gO = a1[3][b] + bias1[3];
        double cn = (double)sigm(gF) * cs1 + (double)(sigm(gI) * tanhf(gG));
        float hn = sigm(gO) * tanhf((float)cn);
        cs1 = cn;
        ast32(h1cur + b * 256 + cc, hn);
      }
    }

    // ---- prediction: h1(191+96jp) = staged H1 this phase ----
    if (rank == 0 && wv == 0 && p >= 193 && ((p - 193) % 96) == 0) {
      int jp = (p - 193) / 96;
      if (jp < 32) {
        int b = lane >> 5, u = lane & 31;   // 32 lanes per batch, 8 cols each
        const float* hb = lds + 640 + b * 320 + (u >> 1) * 20 + 8 * (u & 1);
        fx4 h4a = *(const fx4*)hb;
        fx4 h4b = *(const fx4*)(hb + 4);
        const float* fw = fc_w + u * 8;
        float acc = h4a[0] * fw[0] + h4a[1] * fw[1] + h4a[2] * fw[2] + h4a[3] * fw[3] +
                    h4b[0] * fw[4] + h4b[1] * fw[5] + h4b[2] * fw[6] + h4b[3] * fw[7];
#pragma unroll
        for (int m = 1; m <= 16; m <<= 1) acc += __shfl_xor(acc, m);
        if (u == 0) {
          float pv = acc + fc_b[0];
          ast32(predb + jp * 2 + b, pv);
          out[(2 * c + b) * 96 + jp] = pv;
        }
      }
    }

    // ---- cluster barrier: 8 flags, 8 polling lanes (agent atomics) ----
    __syncthreads();   // drains vmcnt: h atomic stores ACKed at coherence point
    if (tid == 0) {
      __hip_atomic_store(&flags[rank * 16], (unsigned)(p + 1), __ATOMIC_RELAXED,
                         __HIP_MEMORY_SCOPE_AGENT);
    }
    if (wv == 0) {
      const bool act = lane < NWGC;
      const unsigned* myf = flags + (act ? lane : 0) * 16;
      const unsigned tgt = (unsigned)(p + 1);
      while (!__all(!act ||
                    __hip_atomic_load(myf, __ATOMIC_RELAXED,
                                      __HIP_MEMORY_SCOPE_AGENT) >= tgt)) {
      }
    }
    __syncthreads();
  }
}

extern "C" void kernel_launch(void* const* d_in, const int* in_sizes, int n_in,
                              void* d_out, int out_size, void* d_ws, size_t ws_size,
                              hipStream_t stream) {
  const float* x_enc = (const float*)d_in[0];
  const float* Wih0 = (const float*)d_in[4];
  const float* Whh0 = (const float*)d_in[5];
  const float* bih0 = (const float*)d_in[6];
  const float* bhh0 = (const float*)d_in[7];
  const float* Wih1 = (const float*)d_in[8];
  const float* Whh1 = (const float*)d_in[9];
  const float* bih1 = (const float*)d_in[10];
  const float* bhh1 = (const float*)d_in[11];
  const float* fc_w = (const float*)d_in[12];
  const float* fc_b = (const float*)d_in[13];
  float* out = (float*)d_out;
  float* ws = (float*)d_ws;

  hipLaunchKernelGGL(init_kernel, dim3(16), dim3(256), 0, stream, out, ws);

  const int ldsBytes = 82944;   // ~5KB used; >80KB forces 1 WG/CU residency
  static int attrSet = 0;
  if (!attrSet) {
    (void)hipFuncSetAttribute((const void*)lstm_bc,
                              hipFuncAttributeMaxDynamicSharedMemorySize, ldsBytes);
    attrSet = 1;
  }

  hipLaunchKernelGGL(lstm_bc, dim3(256), dim3(512), ldsBytes, stream,
                     x_enc, Wih0, Whh0, bih0, bhh0, Wih1, Whh1, bih1, bhh1,
                     fc_w, fc_b, out, ws);
}